// Round 13
// baseline (672.815 us; speedup 1.0000x reference)
//
#include <hip/hip_runtime.h>
#include <math.h>

// ---------------- problem constants ----------------
constexpr int Bn     = 16;
constexpr int NPG    = 1024;
constexpr int Nn     = Bn * NPG;     // 16384 nodes
constexpr int FIN    = 128;
constexpr int FOUT   = 256;
constexpr int CCAT   = 384;
constexpr int STEPS  = 6;
constexpr int NE     = 262144;

using short8 = __attribute__((ext_vector_type(8))) short;
using f32x4  = __attribute__((ext_vector_type(4))) float;

static __device__ __forceinline__ unsigned short f2bf(float x) {
    union { float f; unsigned u; } v; v.f = x;
    unsigned r = (v.u + 0x7FFFu + ((v.u >> 16) & 1u)) >> 16;
    return (unsigned short)r;
}
static __device__ __forceinline__ float bf2f(unsigned short b) {
    union { unsigned u; float f; } v; v.u = ((unsigned)b) << 16;
    return v.f;
}
static __device__ __forceinline__ float sigm(float x) { return 1.f / (1.f + expf(-x)); }

// async global->LDS, 16B per lane
static __device__ __forceinline__ void gload16(const void* g, void* l) {
    __builtin_amdgcn_global_load_lds(
        (const __attribute__((address_space(1))) void*)g,
        (__attribute__((address_space(3))) void*)l, 16, 0, 0);
}

// ---------------- small utility kernels ----------------

__global__ void cvt_bf(const float* __restrict__ s, unsigned short* __restrict__ d, int n) {
    int i = blockIdx.x * 256 + threadIdx.x;
    if (i < n) d[i] = f2bf(s[i]);
}

// Wcat[k][j] = j<256 ? Whh[k][j] : Wih[k][j-256]   (matches Acat = [h|agg])
__global__ void cvt_wcat(const float* __restrict__ Wih, const float* __restrict__ Whh,
                         unsigned short* __restrict__ Wcat) {
    int o = blockIdx.x * 256 + threadIdx.x;   // 768*512
    int k = o >> 9, j = o & 511;
    float v = (j < 256) ? Whh[(size_t)k * 256 + j] : Wih[(size_t)k * 256 + (j - 256)];
    Wcat[o] = f2bf(v);
}

__global__ void add_bias(const float* __restrict__ a, const float* __restrict__ b,
                         float* __restrict__ o, int n) {
    int i = blockIdx.x * 256 + threadIdx.x;
    if (i < n) o[i] = a[i] + b[i];
}

// conv weight reorder+convert: Wt[c][kb*C+i] = W[c][i][kb]
__global__ void cvt_wconv(const float* __restrict__ W, unsigned short* __restrict__ Wt,
                          int C, int KW, int n) {
    int o = blockIdx.x * 256 + threadIdx.x;
    if (o >= n) return;
    int c = o / (KW * C), rem = o % (KW * C);
    int kb = rem / C, i = rem % C;
    Wt[o] = f2bf(W[(size_t)(c * C + i) * KW + kb]);
}

// h fp32 + h-half of Acat (lda 512)
__global__ void pad_h(const float* __restrict__ f, float* __restrict__ h,
                      unsigned short* __restrict__ Acat) {
    int i = blockIdx.x * 256 + threadIdx.x;
    int k = i & 255, n = i >> 8;
    float v = (k < FIN) ? f[(size_t)n * FIN + k] : 0.f;
    h[i] = v; Acat[(size_t)n * 512 + k] = f2bf(v);
}

// cb[n][c] = c<256 ? Acat[n][c] : bf16(features[n][c-256])
__global__ void build_cb(const unsigned short* __restrict__ Acat, const float* __restrict__ f,
                         unsigned short* __restrict__ cb) {
    int idx = blockIdx.x * 256 + threadIdx.x;
    int c = idx % CCAT, n = idx / CCAT;
    cb[idx] = (c < FOUT) ? Acat[(size_t)n * 512 + c] : f2bf(f[(size_t)n * FIN + (c - FOUT)]);
}

// ---------------- CSR build (once per launch) ----------------

__global__ void edge_count(const int* __restrict__ dst, int* __restrict__ deg) {
    int e = blockIdx.x * 256 + threadIdx.x;
    atomicAdd(&deg[dst[e]], 1);
}

__global__ __launch_bounds__(1024) void scan_deg(const int* __restrict__ deg,
                                                 int* __restrict__ rowptr,
                                                 int* __restrict__ cursor) {
    __shared__ int ps[1024];
    const int t = threadIdx.x;
    int loc[16]; int s = 0;
    const int base = t * 16;
#pragma unroll
    for (int i = 0; i < 16; ++i) { loc[i] = deg[base + i]; s += loc[i]; }
    ps[t] = s;
    __syncthreads();
    for (int off = 1; off < 1024; off <<= 1) {
        int add = (t >= off) ? ps[t - off] : 0;
        __syncthreads();
        ps[t] += add;
        __syncthreads();
    }
    int run = ps[t] - s;
#pragma unroll
    for (int i = 0; i < 16; ++i) { rowptr[base + i] = run; cursor[base + i] = run; run += loc[i]; }
    if (t == 1023) rowptr[16384] = run;
}

__global__ void edge_fill(const int* __restrict__ src, const int* __restrict__ dst,
                          const int* __restrict__ et, int* __restrict__ cursor,
                          int* __restrict__ widx) {
    int e = blockIdx.x * 256 + threadIdx.x;
    int slot = atomicAdd(&cursor[dst[e]], 1);
    widx[slot] = src[e] * 2 + et[e];
}

// ---------------- unified 128x128 MFMA GEMM / implicit conv, T2-swizzled LDS ----------------
static __device__ __forceinline__ void gemm128_body(
    const unsigned short* __restrict__ Ab, const unsigned short* __restrict__ W,
    const float* __restrict__ bias, float* __restrict__ Cf,
    unsigned short* __restrict__ Cb, int Ctap, int lda, int L, int Lv, int N, int K,
    int outBf, int l0, int col0, unsigned short* As, unsigned short* Bs) {
    const int t = threadIdx.x;
    const int w = t >> 6, l = t & 63;
    const int lr = l & 15, lhi = l >> 4;
    const int wr = w >> 1, wc = w & 1;
    const int srow8 = l >> 3;
    const int scole = ((l & 7) ^ srow8) * 8;       // pre-swizzled global col (rule #21)
    const int lx7 = l & 7;

    f32x4 acc[4][4] = {};

    for (int k0 = 0; k0 < K; k0 += 64) {
        const int kb = k0 / Ctap;                  // conv tap (0 for plain GEMM)
        const int i0 = k0 - kb * Ctap;
        __syncthreads();
#pragma unroll
        for (int p = 0; p < 4; ++p) {
            const int r = w * 32 + p * 8;
            int srow = l0 + r + srow8 + kb;
            srow = srow < L ? srow : L - 1;
            gload16(Ab + (size_t)srow * lda + i0 + scole, &As[r * 64]);
            gload16(W + (size_t)(col0 + r + srow8) * K + k0 + scole, &Bs[r * 64]);
        }
        __syncthreads();
        const int abase = (wr * 64 + lr) * 64;
        const int bbase = (wc * 64 + lr) * 64;
#pragma unroll
        for (int kk = 0; kk < 2; ++kk) {
            const int soff = ((kk * 4 + lhi) ^ lx7) * 8;
            short8 af[4], bw[4];
#pragma unroll
            for (int fi = 0; fi < 4; ++fi)
                af[fi] = *(const short8*)&As[abase + fi * 1024 + soff];
#pragma unroll
            for (int fj = 0; fj < 4; ++fj)
                bw[fj] = *(const short8*)&Bs[bbase + fj * 1024 + soff];
#pragma unroll
            for (int fi = 0; fi < 4; ++fi)
#pragma unroll
                for (int fj = 0; fj < 4; ++fj)
                    acc[fi][fj] = __builtin_amdgcn_mfma_f32_16x16x32_bf16(
                        af[fi], bw[fj], acc[fi][fj], 0, 0, 0);
        }
    }
    const int rb = lhi * 4;
#pragma unroll
    for (int fi = 0; fi < 4; ++fi)
#pragma unroll
        for (int fj = 0; fj < 4; ++fj) {
            const int gcol = col0 + wc * 64 + fj * 16 + lr;
            const float bv = bias[gcol];
#pragma unroll
            for (int rr = 0; rr < 4; ++rr) {
                const int grow = l0 + wr * 64 + fi * 16 + rb + rr;
                if (grow < Lv) {
                    float v = acc[fi][fj][rr] + bv;
                    const size_t o = (size_t)grow * N + gcol;
                    if (outBf) Cb[o] = f2bf(v);
                    else       Cf[o] = v;
                }
            }
        }
}

// plain entry (convs, batched via z)
__global__ __launch_bounds__(256) void gemm128(
    const unsigned short* __restrict__ A, const unsigned short* __restrict__ W,
    const float* __restrict__ bias, float* __restrict__ Cf,
    unsigned short* __restrict__ Cb, int Ctap, int lda, int L, int Lv, int N, int K,
    int outBf) {
    __shared__ unsigned short As[128 * 64];
    __shared__ unsigned short Bs[128 * 64];
    const size_t zo = (size_t)blockIdx.z;
    gemm128_body(A + zo * (size_t)L * lda, W, bias,
                 Cf ? Cf + zo * (size_t)Lv * N : nullptr,
                 Cb ? Cb + zo * (size_t)Lv * N : nullptr,
                 Ctap, lda, L, Lv, N, K, outBf,
                 blockIdx.y * 128, blockIdx.x * 128, As, Bs);
}

// XCD-affine swizzled entry (GGNN Wh GEMM): all x-tiles of a row-panel -> same XCD
__global__ __launch_bounds__(256) void gemm128_swz(
    const unsigned short* __restrict__ A, const unsigned short* __restrict__ W,
    const float* __restrict__ bias, unsigned short* __restrict__ Cb,
    int lda, int N, int K) {
    __shared__ unsigned short As[128 * 64];
    __shared__ unsigned short Bs[128 * 64];
    const int gX = gridDim.x;
    const int hId = blockIdx.x + gX * blockIdx.y;
    const int xcd = hId & 7, tt = hId >> 3;
    const int bx = tt % gX, by = xcd + 8 * (tt / gX);
    gemm128_body(A, W, bias, nullptr, Cb, lda, lda, Nn, Nn, N, K, 1,
                 by * 128, bx * 128, As, Bs);
}

// ---------------- fused gates GEMM + GRU epilogue, 2-phase pipelined ----------------
// Block: 64 rows x 64 channels, 4 gate groups; LDS double-buffered (80 KB).
// Per K-step: STAGE(next, buf^1) -> ds_read/MFMA(buf) -> __syncthreads (1 barrier/step).
__global__ __launch_bounds__(256) void gemm_gru(
    const unsigned short* __restrict__ Acat, const unsigned short* __restrict__ Wcat,
    const unsigned short* __restrict__ Whg, const float* __restrict__ bias_s,
    const float* __restrict__ bias_g, float* __restrict__ h,
    unsigned short* __restrict__ Anext) {
    __shared__ unsigned short As[2][64 * 64];    // 16 KB
    __shared__ unsigned short Bs[2][256 * 64];   // 64 KB
    const int hId = blockIdx.x + 4 * blockIdx.y;
    const int xcd = hId & 7, tt = hId >> 3;        // tt 0..127
    const int bx = tt & 3, by = xcd + 8 * (tt >> 2);
    const int l0 = by * 64, c0 = bx * 64;

    const int t = threadIdx.x;
    const int w = t >> 6, l = t & 63;
    const int lr = l & 15, lhi = l >> 4;
    const int srow8 = l >> 3;
    const int scole = ((l & 7) ^ srow8) * 8;
    const int lx7 = l & 7;

    f32x4 acc[16] = {};    // [group*4+colfrag]

#define STAGE_GRU(K0V, ASB, BSB)                                                     \
    {                                                                                \
        const int _k0 = (K0V);                                                       \
        _Pragma("unroll")                                                            \
        for (int p = 0; p < 2; ++p) {                                                \
            const int r = w * 16 + p * 8;                                            \
            gload16(Acat + (size_t)(l0 + r + srow8) * 512 + _k0 + scole,             \
                    &(ASB)[r * 64]);                                                 \
        }                                                                            \
        _Pragma("unroll")                                                            \
        for (int p = 0; p < 8; ++p) {                                                \
            const int r = w * 64 + p * 8;                                            \
            if (r < 192) {                                                           \
                const int g = r >> 6;                                                \
                const int cr = (r & 63) + srow8;                                     \
                gload16(Wcat + (size_t)(g * 256 + c0 + cr) * 512 + _k0 + scole,      \
                        &(BSB)[r * 64]);                                             \
            } else if (_k0 < 256) {                                                  \
                const int cr = (r - 192) + srow8;                                    \
                gload16(Whg + (size_t)(c0 + cr) * 256 + _k0 + scole,                 \
                        &(BSB)[r * 64]);                                             \
            }                                                                        \
        }                                                                            \
    }

    STAGE_GRU(0, As[0], Bs[0]);
    __syncthreads();

#pragma unroll
    for (int k0 = 0; k0 < 512; k0 += 64) {
        const int cur = (k0 >> 6) & 1;
        if (k0 + 64 < 512) STAGE_GRU(k0 + 64, As[cur ^ 1], Bs[cur ^ 1]);
        const unsigned short* Asc = As[cur];
        const unsigned short* Bsc = Bs[cur];
        const int abase = (w * 16 + lr) * 64;
#pragma unroll
        for (int kk = 0; kk < 2; ++kk) {
            const int soff = ((kk * 4 + lhi) ^ lx7) * 8;
            short8 a0 = *(const short8*)&Asc[abase + soff];
#pragma unroll
            for (int g = 0; g < 4; ++g) {
                if (!(g == 3 && k0 >= 256)) {
#pragma unroll
                    for (int fj = 0; fj < 4; ++fj) {
                        short8 bb = *(const short8*)&Bsc[(g * 64 + fj * 16 + lr) * 64 + soff];
                        acc[g * 4 + fj] = __builtin_amdgcn_mfma_f32_16x16x32_bf16(
                            a0, bb, acc[g * 4 + fj], 0, 0, 0);
                    }
                }
            }
        }
        __syncthreads();   // drains this step's STAGE (vmcnt) + compute lgkm; flips buffer
    }
#undef STAGE_GRU

    // GRU epilogue: fragment row = lhi*4+rr, channel col = lane&15
    const int rb = lhi * 4;
#pragma unroll
    for (int fj = 0; fj < 4; ++fj) {
        const int c = c0 + fj * 16 + lr;
        const float br = bias_s[c];
        const float bz = bias_s[256 + c];
        const float bg = bias_s[512 + c];
        const float bh = bias_g[c];
#pragma unroll
        for (int rr = 0; rr < 4; ++rr) {
            const int grow = l0 + w * 16 + rb + rr;
            float sr = acc[0 * 4 + fj][rr] + br;
            float sz = acc[1 * 4 + fj][rr] + bz;
            float sg = acc[2 * 4 + fj][rr] + bg;
            float hg = acc[3 * 4 + fj][rr] + bh;
            float r = sigm(sr), z = sigm(sz);
            float nn = tanhf(sg - (1.f - r) * hg);
            const size_t ho = (size_t)grow * 256 + c;
            float hv = (1.f - z) * nn + z * h[ho];
            h[ho] = hv;
            Anext[(size_t)grow * 512 + c] = f2bf(hv);
        }
    }
}

// ---------------- CSR gather aggregation (into agg-half of Acat) ----------------
// Unrolled x4: 4 independent row-loads in flight per iteration (latency hiding).
__global__ __launch_bounds__(64) void gather_agg(
    const unsigned short* __restrict__ Whb, const int* __restrict__ rowptr,
    const int* __restrict__ widx, unsigned short* __restrict__ Acat) {
    const int n = blockIdx.x, t = threadIdx.x;
    const int s0 = rowptr[n], s1 = rowptr[n + 1];
    float p0[4] = {}, p1[4] = {}, p2[4] = {}, p3[4] = {};
    int s = s0;
    for (; s + 4 <= s1; s += 4) {
        const int w0 = widx[s], w1 = widx[s + 1], w2 = widx[s + 2], w3 = widx[s + 3];
        const ushort4 v0 = *(const ushort4*)(Whb + (size_t)w0 * 256 + t * 4);
        const ushort4 v1 = *(const ushort4*)(Whb + (size_t)w1 * 256 + t * 4);
        const ushort4 v2 = *(const ushort4*)(Whb + (size_t)w2 * 256 + t * 4);
        const ushort4 v3 = *(const ushort4*)(Whb + (size_t)w3 * 256 + t * 4);
        p0[0] += bf2f(v0.x); p0[1] += bf2f(v0.y); p0[2] += bf2f(v0.z); p0[3] += bf2f(v0.w);
        p1[0] += bf2f(v1.x); p1[1] += bf2f(v1.y); p1[2] += bf2f(v1.z); p1[3] += bf2f(v1.w);
        p2[0] += bf2f(v2.x); p2[1] += bf2f(v2.y); p2[2] += bf2f(v2.z); p2[3] += bf2f(v2.w);
        p3[0] += bf2f(v3.x); p3[1] += bf2f(v3.y); p3[2] += bf2f(v3.z); p3[3] += bf2f(v3.w);
    }
    for (; s < s1; ++s) {
        const int wi = widx[s];
        const ushort4 v = *(const ushort4*)(Whb + (size_t)wi * 256 + t * 4);
        p0[0] += bf2f(v.x); p0[1] += bf2f(v.y); p0[2] += bf2f(v.z); p0[3] += bf2f(v.w);
    }
    ushort4 o;
    o.x = f2bf(p0[0] + p1[0] + p2[0] + p3[0]);
    o.y = f2bf(p0[1] + p1[1] + p2[1] + p3[1]);
    o.z = f2bf(p0[2] + p1[2] + p2[2] + p3[2]);
    o.w = f2bf(p0[3] + p1[3] + p2[3] + p3[3]);
    *(ushort4*)(Acat + (size_t)n * 512 + 256 + t * 4) = o;
}

// ---------------- BN stats: parallel 2-level deterministic reduction ----------------
constexpr int NCHUNK = 128;
__global__ __launch_bounds__(256) void bn_part_cl(
    const float* __restrict__ X, float* __restrict__ pS, float* __restrict__ pQ,
    int C, int totalRows, int rowsPerChunk) {
    const int t  = threadIdx.x;
    const int cq = t & 31, rl = t >> 5;
    const int c0 = blockIdx.x * 128 + cq * 4;
    const int r0 = blockIdx.y * rowsPerChunk;
    const int r1 = min(r0 + rowsPerChunk, totalRows);
    float s0 = 0, s1 = 0, s2 = 0, s3 = 0, q0 = 0, q1 = 0, q2 = 0, q3 = 0;
    for (int r = r0 + rl; r < r1; r += 8) {
        float4 v = *(const float4*)(X + (size_t)r * C + c0);
        s0 += v.x; s1 += v.y; s2 += v.z; s3 += v.w;
        q0 += v.x * v.x; q1 += v.y * v.y; q2 += v.z * v.z; q3 += v.w * v.w;
    }
    __shared__ float ls[8][128], lq[8][128];
    ls[rl][cq * 4 + 0] = s0; ls[rl][cq * 4 + 1] = s1;
    ls[rl][cq * 4 + 2] = s2; ls[rl][cq * 4 + 3] = s3;
    lq[rl][cq * 4 + 0] = q0; lq[rl][cq * 4 + 1] = q1;
    lq[rl][cq * 4 + 2] = q2; lq[rl][cq * 4 + 3] = q3;
    __syncthreads();
    if (rl == 0) {
#pragma unroll
        for (int i = 0; i < 4; ++i) {
            const int c = cq * 4 + i;
            float ss = 0, qq = 0;
#pragma unroll
            for (int j = 0; j < 8; ++j) { ss += ls[j][c]; qq += lq[j][c]; }
            pS[(size_t)blockIdx.y * C + c0 + i] = ss;
            pQ[(size_t)blockIdx.y * C + c0 + i] = qq;
        }
    }
}

__global__ __launch_bounds__(128) void bn_reduce_cl(
    const float* __restrict__ pS, const float* __restrict__ pQ,
    float* __restrict__ mean, float* __restrict__ var, int C, int totalRows) {
    const int c = blockIdx.x, t = threadIdx.x;
    __shared__ float rs[128], rq[128];
    rs[t] = pS[(size_t)t * C + c];
    rq[t] = pQ[(size_t)t * C + c];
    __syncthreads();
    for (int st = 64; st; st >>= 1) {
        if (t < st) { rs[t] += rs[t + st]; rq[t] += rq[t + st]; }
        __syncthreads();
    }
    if (t == 0) {
        float m = rs[0] / totalRows;
        mean[c] = m;
        var[c]  = rq[0] / totalRows - m * m;
    }
}

// ---------------- fused BN + ReLU + maxpool (channel-last) ----------------
__global__ void bnp_cl(const float* __restrict__ X, const float* __restrict__ mean,
                       const float* __restrict__ var, const float* __restrict__ g,
                       const float* __restrict__ bta, float* __restrict__ Of,
                       unsigned short* __restrict__ Ob, int C, int Lin, int Lout,
                       int Kp, int outBf) {
    int idx = blockIdx.x * 256 + threadIdx.x;
    if (idx >= Bn * Lout * C) return;
    int c = idx % C, j = (idx / C) % Lout, b = idx / (C * Lout);
    float sc = g[c] * rsqrtf(var[c] + 1e-5f);
    float sh = bta[c] - mean[c] * sc;
    const float* xb = X + ((size_t)b * Lin + j * 2) * C + c;
    float m = 0.f;
    for (int k = 0; k < Kp; ++k) m = fmaxf(m, xb[(size_t)k * C] * sc + sh);
    if (outBf) Ob[idx] = f2bf(m);
    else       Of[idx] = m;
}

// ---------------- final gating ----------------
__global__ void final_dot(const float* __restrict__ Y2, const float* __restrict__ Z2,
                          const float* __restrict__ wy, const float* __restrict__ by,
                          const float* __restrict__ wz, const float* __restrict__ bz,
                          float* __restrict__ prod) {
    const int b = blockIdx.y, j = blockIdx.x, t = threadIdx.x;
    float p0 = 0, p1 = 0, q0 = 0, q1 = 0;
    const float* yrow = Y2 + (size_t)(b * 255 + j) * FOUT;
    const float* zrow = Z2 + (size_t)(b * 255 + j) * CCAT;
    for (int c = t; c < FOUT; c += 128) {
        float v = yrow[c];
        p0 += v * wy[c]; p1 += v * wy[FOUT + c];
    }
    for (int c = t; c < CCAT; c += 128) {
        float v = zrow[c];
        q0 += v * wz[c]; q1 += v * wz[CCAT + c];
    }
    __shared__ float r0[128], r1[128], r2[128], r3[128];
    r0[t] = p0; r1[t] = p1; r2[t] = q0; r3[t] = q1;
    __syncthreads();
    for (int s = 64; s; s >>= 1) {
        if (t < s) { r0[t] += r0[t + s]; r1[t] += r1[t + s]; r2[t] += r2[t + s]; r3[t] += r3[t + s]; }
        __syncthreads();
    }
    if (t == 0) {
        float y0 = r0[0] + by[0], y1 = r1[0] + by[1];
        float z0 = r2[0] + bz[0], z1 = r3[0] + bz[1];
        prod[((size_t)b * 255 + j) * 2 + 0] = y0 * z0;
        prod[((size_t)b * 255 + j) * 2 + 1] = y1 * z1;
    }
}

__global__ void final_out(const float* __restrict__ prod, float* __restrict__ out) {
    const int b = blockIdx.x, t = threadIdx.x;
    const int w = t >> 6, lane = t & 63;
    float s = 0.f;
    for (int j = lane; j < 255; j += 64) s += prod[((size_t)b * 255 + j) * 2 + w];
#pragma unroll
    for (int off = 32; off; off >>= 1) s += __shfl_down(s, off);
    if (lane == 0) out[b * 2 + w] = 1.f / (1.f + expf(-s / 255.f));
}

// ---------------- launch ----------------
extern "C" void kernel_launch(void* const* d_in, const int* in_sizes, int n_in,
                              void* d_out, int out_size, void* d_ws, size_t ws_size,
                              hipStream_t stream) {
    (void)in_sizes; (void)n_in; (void)out_size; (void)ws_size;
    const float* features = (const float*)d_in[0];
    const int*   src      = (const int*)d_in[1];
    const int*   dst      = (const int*)d_in[2];
    const int*   etype    = (const int*)d_in[3];
    const float* W_lin    = (const float*)d_in[4];
    const float* b_lin    = (const float*)d_in[5];
    const float* W_ih     = (const float*)d_in[6];
    const float* W_hh     = (const float*)d_in[7];
    const float* b_ih     = (const float*)d_in[8];
    const float* b_hh     = (const float*)d_in[9];
    const float* conv1_w  = (const float*)d_in[10];
    const float* conv1_b  = (const float*)d_in[11];
    const float* conv2_w  = (const float*)d_in[12];
    const float* conv2_b  = (const float*)d_in[13];
    const float* convc1_w = (const float*)d_in[14];
    const float* convc1_b = (const float*)d_in[15];
    const float* convc2_w = (const float*)d_in[16];
    const float* convc2_b = (const float*)d_in[17];
    const float* bn_g     = (const float*)d_in[18];
    const float* bn_b     = (const float*)d_in[19];
    const float* bnc_g    = (const float*)d_in[20];
    const float* bnc_b    = (const float*)d_in[21];
    const float* mlpy_w   = (const float*)d_in[22];
    const float* mlpy_b   = (const float*)d_in[23];
    const float* mlpz_w   = (const float*)d_in[24];
    const float* mlpz_b   = (const float*)d_in[25];

    float* ws = (float*)d_ws;
    // ---- layout (float offsets) ----
    float*          h      = ws;                                 // [0, 4.19M)
    unsigned short* Acat0  = (unsigned short*)(ws + 4194304);    // [16384][512] bf16
    float*          bufA   = ws + 8388608;                       // 12.58M
    float*          bufB   = ws + 20971520;                      // 12.58M
    unsigned short* Wlin_b = (unsigned short*)(ws + 33554432);   // [512][256]
    unsigned short* Whh_b  = (unsigned short*)(ws + 33554432) + 131072;  // [768][256]
    unsigned short* Wcat_b = (unsigned short*)(ws + 33554432) + 327680;  // [768][512]
    float*          bias_s = ws + 33950000;                      // 768 f (clean region)
    int*            ib     = (int*)(ws + 34000000);
    int* deg    = ib;
    int* cursor = ib + 16384;
    int* rowptr = ib + 32768;
    int* widx   = ib + 49160;
    float* sreg = ws + 34500000;
    float* meanb = sreg;
    float* varb  = sreg + 384;
    float* pS    = sreg + 1024;
    float* pQ    = sreg + 50176;
    float* prod  = sreg + 99328;

    unsigned short* Whb   = (unsigned short*)bufA;               // [16384][512] bf16
    unsigned short* Acat1 = (unsigned short*)(bufA + 4194304);   // [16384][512] bf16 (ping-pong)
    const unsigned short* Whg = Whh_b + 512 * 256;               // rows 512..767 of Whh

    // ---- weight conversion + CSR build ----
    cvt_bf<<<512,  256, 0, stream>>>(W_lin, Wlin_b, 131072);
    cvt_bf<<<768,  256, 0, stream>>>(W_hh,  Whh_b,  196608);
    cvt_wcat<<<1536, 256, 0, stream>>>(W_ih, W_hh, Wcat_b);
    add_bias<<<3, 256, 0, stream>>>(b_ih, b_hh, bias_s, 768);
    pad_h<<<Nn * FOUT / 256, 256, 0, stream>>>(features, h, Acat0);

    hipMemsetAsync(deg, 0, 16384 * sizeof(int), stream);
    edge_count<<<NE / 256, 256, 0, stream>>>(dst, deg);
    scan_deg<<<1, 1024, 0, stream>>>(deg, rowptr, cursor);
    edge_fill<<<NE / 256, 256, 0, stream>>>(src, dst, etype, cursor, widx);

    // ---- GGNN steps (Acat ping-pong; STEPS even -> final h-half in Acat0) ----
    unsigned short* Acur = Acat0;
    unsigned short* Anxt = Acat1;
    for (int s6 = 0; s6 < STEPS; ++s6) {
        gemm128_swz<<<dim3(4, 128), 256, 0, stream>>>(
            Acur, Wlin_b, b_lin, Whb, 512, 512, 256);
        gather_agg<<<Nn, 64, 0, stream>>>(Whb, rowptr, widx, Acur);
        gemm_gru<<<dim3(4, 256), 256, 0, stream>>>(
            Acur, Wcat_b, Whg, bias_s, b_hh + 512, h, Anxt);
        unsigned short* tmp = Acur; Acur = Anxt; Anxt = tmp;
    }

    // ---- conv-phase layout (channel-last); Acat1 dead after last step ----
    unsigned short* cb    = (unsigned short*)ws;                 // [16384][384] bf16 (over dead h)
    float*          Yc1   = bufA;                                // [16352][256] f32
    unsigned short* P1y   = (unsigned short*)(bufA + 4186112);   // [8160][256] bf16
    float*          Yc2   = bufA + 5230592;                      // [8160][256] f32
    float*          Y2    = bufA + 7319552;                      // [4080][256] f32
    float*          Z2    = bufA + 8364032;                      // [4080][384] f32
    float*          Zc1   = bufB;                                // [16352][384] f32
    unsigned short* P1z   = (unsigned short*)(bufB + 6279168);   // [8160][384] bf16
    float*          Zc2   = bufB + 7845888;                      // [8160][384] f32
    unsigned short* Wcv   = (unsigned short*)(bufB + 11000000);
    unsigned short* c1b   = Wcv;                                 // [256][768]
    unsigned short* c2b   = Wcv + 196608;                        // [256][256]
    unsigned short* cc1b  = Wcv + 262144;                        // [384][1152]
    unsigned short* cc2b  = Wcv + 704512;                        // [384][384]

    cvt_wconv<<<768,  256, 0, stream>>>(conv1_w,  c1b,  FOUT, 3, FOUT * FOUT * 3);
    cvt_wconv<<<256,  256, 0, stream>>>(conv2_w,  c2b,  FOUT, 1, FOUT * FOUT);
    cvt_wconv<<<1728, 256, 0, stream>>>(convc1_w, cc1b, CCAT, 3, CCAT * CCAT * 3);
    cvt_wconv<<<576,  256, 0, stream>>>(convc2_w, cc2b, CCAT, 1, CCAT * CCAT);
    build_cb<<<Nn * CCAT / 256, 256, 0, stream>>>(Acat0, features, cb);

    const int rows1 = Bn * 1022;
    const int rows2 = Bn * 510;
    const int rpc1  = (rows1 + NCHUNK - 1) / NCHUNK;
    const int rpc2  = (rows2 + NCHUNK - 1) / NCHUNK;

    // ---- Y branch (conv1 reads h-half of Acat0, lda=512) ----
    gemm128<<<dim3(2, 8, Bn), 256, 0, stream>>>(Acat0, c1b, conv1_b, Yc1, nullptr,
                                                FOUT, 512, 1024, 1022, FOUT, 768, 0);
    bn_part_cl<<<dim3(FOUT / 128, NCHUNK), 256, 0, stream>>>(Yc1, pS, pQ, FOUT, rows1, rpc1);
    bn_reduce_cl<<<FOUT, 128, 0, stream>>>(pS, pQ, meanb, varb, FOUT, rows1);
    bnp_cl<<<(Bn * 510 * FOUT + 255) / 256, 256, 0, stream>>>(
        Yc1, meanb, varb, bn_g, bn_b, nullptr, P1y, FOUT, 1022, 510, 3, 1);
    gemm128<<<dim3(2, 4, Bn), 256, 0, stream>>>(P1y, c2b, conv2_b, Yc2, nullptr,
                                                FOUT, 256, 510, 510, FOUT, 256, 0);
    bn_part_cl<<<dim3(FOUT / 128, NCHUNK), 256, 0, stream>>>(Yc2, pS, pQ, FOUT, rows2, rpc2);
    bn_reduce_cl<<<FOUT, 128, 0, stream>>>(pS, pQ, meanb, varb, FOUT, rows2);
    bnp_cl<<<(Bn * 255 * FOUT + 255) / 256, 256, 0, stream>>>(
        Yc2, meanb, varb, bn_g, bn_b, Y2, nullptr, FOUT, 510, 255, 2, 0);

    // ---- Z branch ----
    gemm128<<<dim3(3, 8, Bn), 256, 0, stream>>>(cb, cc1b, convc1_b, Zc1, nullptr,
                                                CCAT, 384, 1024, 1022, CCAT, 1152, 0);
    bn_part_cl<<<dim3(CCAT / 128, NCHUNK), 256, 0, stream>>>(Zc1, pS, pQ, CCAT, rows1, rpc1);
    bn_reduce_cl<<<CCAT, 128, 0, stream>>>(pS, pQ, meanb, varb, CCAT, rows1);
    bnp_cl<<<(Bn * 510 * CCAT + 255) / 256, 256, 0, stream>>>(
        Zc1, meanb, varb, bnc_g, bnc_b, nullptr, P1z, CCAT, 1022, 510, 3, 1);
    gemm128<<<dim3(3, 4, Bn), 256, 0, stream>>>(P1z, cc2b, convc2_b, Zc2, nullptr,
                                                CCAT, 384, 510, 510, CCAT, 384, 0);
    bn_part_cl<<<dim3(CCAT / 128, NCHUNK), 256, 0, stream>>>(Zc2, pS, pQ, CCAT, rows2, rpc2);
    bn_reduce_cl<<<CCAT, 128, 0, stream>>>(pS, pQ, meanb, varb, CCAT, rows2);
    bnp_cl<<<(Bn * 255 * CCAT + 255) / 256, 256, 0, stream>>>(
        Zc2, meanb, varb, bnc_g, bnc_b, Z2, nullptr, CCAT, 510, 255, 2, 0);

    // ---- gating + mean + sigmoid ----
    final_dot<<<dim3(255, Bn), 128, 0, stream>>>(Y2, Z2, mlpy_w, mlpy_b, mlpz_w, mlpz_b, prod);
    final_out<<<Bn, 128, 0, stream>>>(prod, (float*)d_out);
}

// Round 14
// 608.982 us; speedup vs baseline: 1.1048x; 1.1048x over previous
//
#include <hip/hip_runtime.h>
#include <math.h>

// ---------------- problem constants ----------------
constexpr int Bn     = 16;
constexpr int NPG    = 1024;
constexpr int Nn     = Bn * NPG;     // 16384 nodes
constexpr int FIN    = 128;
constexpr int FOUT   = 256;
constexpr int CCAT   = 384;
constexpr int STEPS  = 6;
constexpr int NE     = 262144;

using short8 = __attribute__((ext_vector_type(8))) short;
using f32x4  = __attribute__((ext_vector_type(4))) float;

static __device__ __forceinline__ unsigned short f2bf(float x) {
    union { float f; unsigned u; } v; v.f = x;
    unsigned r = (v.u + 0x7FFFu + ((v.u >> 16) & 1u)) >> 16;
    return (unsigned short)r;
}
static __device__ __forceinline__ float bf2f(unsigned short b) {
    union { unsigned u; float f; } v; v.u = ((unsigned)b) << 16;
    return v.f;
}
static __device__ __forceinline__ float sigm(float x) { return 1.f / (1.f + expf(-x)); }

// async global->LDS, 16B per lane
static __device__ __forceinline__ void gload16(const void* g, void* l) {
    __builtin_amdgcn_global_load_lds(
        (const __attribute__((address_space(1))) void*)g,
        (__attribute__((address_space(3))) void*)l, 16, 0, 0);
}

// ---------------- small utility kernels ----------------

__global__ void cvt_bf(const float* __restrict__ s, unsigned short* __restrict__ d, int n) {
    int i = blockIdx.x * 256 + threadIdx.x;
    if (i < n) d[i] = f2bf(s[i]);
}

// Wcat[k][j] = j<256 ? Whh[k][j] : Wih[k][j-256]   (matches Acat = [h|agg])
__global__ void cvt_wcat(const float* __restrict__ Wih, const float* __restrict__ Whh,
                         unsigned short* __restrict__ Wcat) {
    int o = blockIdx.x * 256 + threadIdx.x;   // 768*512
    int k = o >> 9, j = o & 511;
    float v = (j < 256) ? Whh[(size_t)k * 256 + j] : Wih[(size_t)k * 256 + (j - 256)];
    Wcat[o] = f2bf(v);
}

__global__ void add_bias(const float* __restrict__ a, const float* __restrict__ b,
                         float* __restrict__ o, int n) {
    int i = blockIdx.x * 256 + threadIdx.x;
    if (i < n) o[i] = a[i] + b[i];
}

// conv weight reorder+convert: Wt[c][kb*C+i] = W[c][i][kb]
__global__ void cvt_wconv(const float* __restrict__ W, unsigned short* __restrict__ Wt,
                          int C, int KW, int n) {
    int o = blockIdx.x * 256 + threadIdx.x;
    if (o >= n) return;
    int c = o / (KW * C), rem = o % (KW * C);
    int kb = rem / C, i = rem % C;
    Wt[o] = f2bf(W[(size_t)(c * C + i) * KW + kb]);
}

// h fp32 + h-half of Acat (lda 512)
__global__ void pad_h(const float* __restrict__ f, float* __restrict__ h,
                      unsigned short* __restrict__ Acat) {
    int i = blockIdx.x * 256 + threadIdx.x;
    int k = i & 255, n = i >> 8;
    float v = (k < FIN) ? f[(size_t)n * FIN + k] : 0.f;
    h[i] = v; Acat[(size_t)n * 512 + k] = f2bf(v);
}

// cb[n][c] = c<256 ? Acat[n][c] : bf16(features[n][c-256])
__global__ void build_cb(const unsigned short* __restrict__ Acat, const float* __restrict__ f,
                         unsigned short* __restrict__ cb) {
    int idx = blockIdx.x * 256 + threadIdx.x;
    int c = idx % CCAT, n = idx / CCAT;
    cb[idx] = (c < FOUT) ? Acat[(size_t)n * 512 + c] : f2bf(f[(size_t)n * FIN + (c - FOUT)]);
}

// ---------------- CSR build (once per launch) ----------------

__global__ void edge_count(const int* __restrict__ dst, int* __restrict__ deg) {
    int e = blockIdx.x * 256 + threadIdx.x;
    atomicAdd(&deg[dst[e]], 1);
}

__global__ __launch_bounds__(1024) void scan_deg(const int* __restrict__ deg,
                                                 int* __restrict__ rowptr,
                                                 int* __restrict__ cursor) {
    __shared__ int ps[1024];
    const int t = threadIdx.x;
    int loc[16]; int s = 0;
    const int base = t * 16;
#pragma unroll
    for (int i = 0; i < 16; ++i) { loc[i] = deg[base + i]; s += loc[i]; }
    ps[t] = s;
    __syncthreads();
    for (int off = 1; off < 1024; off <<= 1) {
        int add = (t >= off) ? ps[t - off] : 0;
        __syncthreads();
        ps[t] += add;
        __syncthreads();
    }
    int run = ps[t] - s;
#pragma unroll
    for (int i = 0; i < 16; ++i) { rowptr[base + i] = run; cursor[base + i] = run; run += loc[i]; }
    if (t == 1023) rowptr[16384] = run;
}

__global__ void edge_fill(const int* __restrict__ src, const int* __restrict__ dst,
                          const int* __restrict__ et, int* __restrict__ cursor,
                          int* __restrict__ widx) {
    int e = blockIdx.x * 256 + threadIdx.x;
    int slot = atomicAdd(&cursor[dst[e]], 1);
    widx[slot] = src[e] * 2 + et[e];
}

// ---------------- unified 128x128 MFMA GEMM / implicit conv, T2-swizzled LDS ----------------
static __device__ __forceinline__ void gemm128_body(
    const unsigned short* __restrict__ Ab, const unsigned short* __restrict__ W,
    const float* __restrict__ bias, float* __restrict__ Cf,
    unsigned short* __restrict__ Cb, int Ctap, int lda, int L, int Lv, int N, int K,
    int outBf, int l0, int col0, unsigned short* As, unsigned short* Bs) {
    const int t = threadIdx.x;
    const int w = t >> 6, l = t & 63;
    const int lr = l & 15, lhi = l >> 4;
    const int wr = w >> 1, wc = w & 1;
    const int srow8 = l >> 3;
    const int scole = ((l & 7) ^ srow8) * 8;       // pre-swizzled global col (rule #21)
    const int lx7 = l & 7;

    f32x4 acc[4][4] = {};

    for (int k0 = 0; k0 < K; k0 += 64) {
        const int kb = k0 / Ctap;                  // conv tap (0 for plain GEMM)
        const int i0 = k0 - kb * Ctap;
        __syncthreads();
#pragma unroll
        for (int p = 0; p < 4; ++p) {
            const int r = w * 32 + p * 8;
            int srow = l0 + r + srow8 + kb;
            srow = srow < L ? srow : L - 1;
            gload16(Ab + (size_t)srow * lda + i0 + scole, &As[r * 64]);
            gload16(W + (size_t)(col0 + r + srow8) * K + k0 + scole, &Bs[r * 64]);
        }
        __syncthreads();
        const int abase = (wr * 64 + lr) * 64;
        const int bbase = (wc * 64 + lr) * 64;
#pragma unroll
        for (int kk = 0; kk < 2; ++kk) {
            const int soff = ((kk * 4 + lhi) ^ lx7) * 8;
            short8 af[4], bw[4];
#pragma unroll
            for (int fi = 0; fi < 4; ++fi)
                af[fi] = *(const short8*)&As[abase + fi * 1024 + soff];
#pragma unroll
            for (int fj = 0; fj < 4; ++fj)
                bw[fj] = *(const short8*)&Bs[bbase + fj * 1024 + soff];
#pragma unroll
            for (int fi = 0; fi < 4; ++fi)
#pragma unroll
                for (int fj = 0; fj < 4; ++fj)
                    acc[fi][fj] = __builtin_amdgcn_mfma_f32_16x16x32_bf16(
                        af[fi], bw[fj], acc[fi][fj], 0, 0, 0);
        }
    }
    const int rb = lhi * 4;
#pragma unroll
    for (int fi = 0; fi < 4; ++fi)
#pragma unroll
        for (int fj = 0; fj < 4; ++fj) {
            const int gcol = col0 + wc * 64 + fj * 16 + lr;
            const float bv = bias[gcol];
#pragma unroll
            for (int rr = 0; rr < 4; ++rr) {
                const int grow = l0 + wr * 64 + fi * 16 + rb + rr;
                if (grow < Lv) {
                    float v = acc[fi][fj][rr] + bv;
                    const size_t o = (size_t)grow * N + gcol;
                    if (outBf) Cb[o] = f2bf(v);
                    else       Cf[o] = v;
                }
            }
        }
}

// XCD-affine swizzled entry (GGNN Wh GEMM): all x-tiles of a row-panel -> same XCD
__global__ __launch_bounds__(256) void gemm128_swz(
    const unsigned short* __restrict__ A, const unsigned short* __restrict__ W,
    const float* __restrict__ bias, unsigned short* __restrict__ Cb,
    int lda, int N, int K) {
    __shared__ unsigned short As[128 * 64];
    __shared__ unsigned short Bs[128 * 64];
    const int gX = gridDim.x;
    const int hId = blockIdx.x + gX * blockIdx.y;
    const int xcd = hId & 7, tt = hId >> 3;
    const int bx = tt % gX, by = xcd + 8 * (tt / gX);
    gemm128_body(A, W, bias, nullptr, Cb, lda, lda, Nn, Nn, N, K, 1,
                 by * 128, bx * 128, As, Bs);
}

// two independent conv/GEMM problems in one dispatch (linear grid), fp32 out
__global__ __launch_bounds__(256) void gemm128_pair2(
    const unsigned short* __restrict__ A1, const unsigned short* __restrict__ W1,
    const float* __restrict__ b1, float* __restrict__ C1,
    int Ctap1, int lda1, int L1, int Lv1, int N1, int K1, int nx1, int ny1,
    const unsigned short* __restrict__ A2, const unsigned short* __restrict__ W2,
    const float* __restrict__ b2, float* __restrict__ C2,
    int Ctap2, int lda2, int L2, int Lv2, int N2, int K2, int nx2, int ny2) {
    __shared__ unsigned short As[128 * 64];
    __shared__ unsigned short Bs[128 * 64];
    int id = blockIdx.x;
    const int n1 = nx1 * ny1 * Bn;
    if (id < n1) {
        int x = id % nx1, y = (id / nx1) % ny1, z = id / (nx1 * ny1);
        gemm128_body(A1 + (size_t)z * L1 * lda1, W1, b1,
                     C1 + (size_t)z * Lv1 * N1, nullptr,
                     Ctap1, lda1, L1, Lv1, N1, K1, 0, y * 128, x * 128, As, Bs);
    } else {
        id -= n1;
        int x = id % nx2, y = (id / nx2) % ny2, z = id / (nx2 * ny2);
        gemm128_body(A2 + (size_t)z * L2 * lda2, W2, b2,
                     C2 + (size_t)z * Lv2 * N2, nullptr,
                     Ctap2, lda2, L2, Lv2, N2, K2, 0, y * 128, x * 128, As, Bs);
    }
}

// ---------------- fused gates GEMM + GRU epilogue (64x64 tile, single-buffer) ----------------
__global__ __launch_bounds__(256) void gemm_gru(
    const unsigned short* __restrict__ Acat, const unsigned short* __restrict__ Wcat,
    const unsigned short* __restrict__ Whg, const float* __restrict__ bias_s,
    const float* __restrict__ bias_g, float* __restrict__ h,
    unsigned short* __restrict__ Anext) {
    __shared__ unsigned short As[64 * 64];    //  8 KB
    __shared__ unsigned short Bs[256 * 64];   // 32 KB
    const int hId = blockIdx.x + 4 * blockIdx.y;
    const int xcd = hId & 7, tt = hId >> 3;        // tt 0..127
    const int bx = tt & 3, by = xcd + 8 * (tt >> 2);
    const int l0 = by * 64, c0 = bx * 64;

    const int t = threadIdx.x;
    const int w = t >> 6, l = t & 63;
    const int lr = l & 15, lhi = l >> 4;
    const int srow8 = l >> 3;
    const int scole = ((l & 7) ^ srow8) * 8;
    const int lx7 = l & 7;

    f32x4 acc[16] = {};    // [group*4+colfrag]

#pragma unroll
    for (int k0 = 0; k0 < 512; k0 += 64) {
        __syncthreads();
#pragma unroll
        for (int p = 0; p < 2; ++p) {
            const int r = w * 16 + p * 8;
            gload16(Acat + (size_t)(l0 + r + srow8) * 512 + k0 + scole, &As[r * 64]);
        }
#pragma unroll
        for (int p = 0; p < 8; ++p) {
            const int r = w * 64 + p * 8;          // wave-uniform
            if (r < 192) {
                const int g = r >> 6;
                const int cr = (r & 63) + srow8;
                gload16(Wcat + (size_t)(g * 256 + c0 + cr) * 512 + k0 + scole, &Bs[r * 64]);
            } else if (k0 < 256) {
                const int cr = (r - 192) + srow8;
                gload16(Whg + (size_t)(c0 + cr) * 256 + k0 + scole, &Bs[r * 64]);
            }
        }
        __syncthreads();
        const int abase = (w * 16 + lr) * 64;
#pragma unroll
        for (int kk = 0; kk < 2; ++kk) {
            const int soff = ((kk * 4 + lhi) ^ lx7) * 8;
            short8 a0 = *(const short8*)&As[abase + soff];
#pragma unroll
            for (int g = 0; g < 4; ++g) {
                if (!(g == 3 && k0 >= 256)) {
#pragma unroll
                    for (int fj = 0; fj < 4; ++fj) {
                        short8 bb = *(const short8*)&Bs[(g * 64 + fj * 16 + lr) * 64 + soff];
                        acc[g * 4 + fj] = __builtin_amdgcn_mfma_f32_16x16x32_bf16(
                            a0, bb, acc[g * 4 + fj], 0, 0, 0);
                    }
                }
            }
        }
    }
    // GRU epilogue: fragment row = lhi*4+rr, channel col = lane&15
    const int rb = lhi * 4;
#pragma unroll
    for (int fj = 0; fj < 4; ++fj) {
        const int c = c0 + fj * 16 + lr;
        const float br = bias_s[c];
        const float bz = bias_s[256 + c];
        const float bg = bias_s[512 + c];
        const float bh = bias_g[c];
#pragma unroll
        for (int rr = 0; rr < 4; ++rr) {
            const int grow = l0 + w * 16 + rb + rr;
            float sr = acc[0 * 4 + fj][rr] + br;
            float sz = acc[1 * 4 + fj][rr] + bz;
            float sg = acc[2 * 4 + fj][rr] + bg;
            float hg = acc[3 * 4 + fj][rr] + bh;
            float r = sigm(sr), z = sigm(sz);
            float nn = tanhf(sg - (1.f - r) * hg);
            const size_t ho = (size_t)grow * 256 + c;
            float hv = (1.f - z) * nn + z * h[ho];
            h[ho] = hv;
            Anext[(size_t)grow * 512 + c] = f2bf(hv);
        }
    }
}

// ---------------- CSR gather aggregation (into agg-half of Acat), x4 unrolled ----------------
__global__ __launch_bounds__(64) void gather_agg(
    const unsigned short* __restrict__ Whb, const int* __restrict__ rowptr,
    const int* __restrict__ widx, unsigned short* __restrict__ Acat) {
    const int n = blockIdx.x, t = threadIdx.x;
    const int s0 = rowptr[n], s1 = rowptr[n + 1];
    float p0[4] = {}, p1[4] = {}, p2[4] = {}, p3[4] = {};
    int s = s0;
    for (; s + 4 <= s1; s += 4) {
        const int w0 = widx[s], w1 = widx[s + 1], w2 = widx[s + 2], w3 = widx[s + 3];
        const ushort4 v0 = *(const ushort4*)(Whb + (size_t)w0 * 256 + t * 4);
        const ushort4 v1 = *(const ushort4*)(Whb + (size_t)w1 * 256 + t * 4);
        const ushort4 v2 = *(const ushort4*)(Whb + (size_t)w2 * 256 + t * 4);
        const ushort4 v3 = *(const ushort4*)(Whb + (size_t)w3 * 256 + t * 4);
        p0[0] += bf2f(v0.x); p0[1] += bf2f(v0.y); p0[2] += bf2f(v0.z); p0[3] += bf2f(v0.w);
        p1[0] += bf2f(v1.x); p1[1] += bf2f(v1.y); p1[2] += bf2f(v1.z); p1[3] += bf2f(v1.w);
        p2[0] += bf2f(v2.x); p2[1] += bf2f(v2.y); p2[2] += bf2f(v2.z); p2[3] += bf2f(v2.w);
        p3[0] += bf2f(v3.x); p3[1] += bf2f(v3.y); p3[2] += bf2f(v3.z); p3[3] += bf2f(v3.w);
    }
    for (; s < s1; ++s) {
        const int wi = widx[s];
        const ushort4 v = *(const ushort4*)(Whb + (size_t)wi * 256 + t * 4);
        p0[0] += bf2f(v.x); p0[1] += bf2f(v.y); p0[2] += bf2f(v.z); p0[3] += bf2f(v.w);
    }
    ushort4 o;
    o.x = f2bf(p0[0] + p1[0] + p2[0] + p3[0]);
    o.y = f2bf(p0[1] + p1[1] + p2[1] + p3[1]);
    o.z = f2bf(p0[2] + p1[2] + p2[2] + p3[2]);
    o.w = f2bf(p0[3] + p1[3] + p2[3] + p3[3]);
    *(ushort4*)(Acat + (size_t)n * 512 + 256 + t * 4) = o;
}

// ---------------- paired BN stats (Y & Z branches in one dispatch) ----------------
constexpr int NCHUNK = 128;

static __device__ __forceinline__ void bn_part_body(
    const float* __restrict__ X, float* __restrict__ pS, float* __restrict__ pQ,
    int C, int totalRows, int rowsPerChunk, int bx, int by) {
    const int t  = threadIdx.x;
    const int cq = t & 31, rl = t >> 5;
    const int c0 = bx * 128 + cq * 4;
    const int r0 = by * rowsPerChunk;
    const int r1 = min(r0 + rowsPerChunk, totalRows);
    float s0 = 0, s1 = 0, s2 = 0, s3 = 0, q0 = 0, q1 = 0, q2 = 0, q3 = 0;
    for (int r = r0 + rl; r < r1; r += 8) {
        float4 v = *(const float4*)(X + (size_t)r * C + c0);
        s0 += v.x; s1 += v.y; s2 += v.z; s3 += v.w;
        q0 += v.x * v.x; q1 += v.y * v.y; q2 += v.z * v.z; q3 += v.w * v.w;
    }
    __shared__ float ls[8][128], lq[8][128];
    ls[rl][cq * 4 + 0] = s0; ls[rl][cq * 4 + 1] = s1;
    ls[rl][cq * 4 + 2] = s2; ls[rl][cq * 4 + 3] = s3;
    lq[rl][cq * 4 + 0] = q0; lq[rl][cq * 4 + 1] = q1;
    lq[rl][cq * 4 + 2] = q2; lq[rl][cq * 4 + 3] = q3;
    __syncthreads();
    if (rl == 0) {
#pragma unroll
        for (int i = 0; i < 4; ++i) {
            const int c = cq * 4 + i;
            float ss = 0, qq = 0;
#pragma unroll
            for (int j = 0; j < 8; ++j) { ss += ls[j][c]; qq += lq[j][c]; }
            pS[(size_t)by * C + c0 + i] = ss;
            pQ[(size_t)by * C + c0 + i] = qq;
        }
    }
}

__global__ __launch_bounds__(256) void bn_part_pair(
    const float* __restrict__ X1, float* __restrict__ pS1, float* __restrict__ pQ1, int C1,
    const float* __restrict__ X2, float* __restrict__ pS2, float* __restrict__ pQ2, int C2,
    int totalRows, int rowsPerChunk) {
    int id = blockIdx.x;
    const int n1 = (C1 / 128) * NCHUNK;
    if (id < n1)
        bn_part_body(X1, pS1, pQ1, C1, totalRows, rowsPerChunk, id % (C1 / 128), id / (C1 / 128));
    else {
        id -= n1;
        bn_part_body(X2, pS2, pQ2, C2, totalRows, rowsPerChunk, id % (C2 / 128), id / (C2 / 128));
    }
}

__global__ __launch_bounds__(128) void bn_reduce_pair(
    const float* __restrict__ pS1, const float* __restrict__ pQ1,
    float* __restrict__ mean1, float* __restrict__ var1, int C1,
    const float* __restrict__ pS2, const float* __restrict__ pQ2,
    float* __restrict__ mean2, float* __restrict__ var2, int C2, int totalRows) {
    int c = blockIdx.x;
    const float* pS; const float* pQ; float* mean; float* var; int C;
    if (c < C1) { pS = pS1; pQ = pQ1; mean = mean1; var = var1; C = C1; }
    else { c -= C1; pS = pS2; pQ = pQ2; mean = mean2; var = var2; C = C2; }
    const int t = threadIdx.x;
    __shared__ float rs[128], rq[128];
    rs[t] = pS[(size_t)t * C + c];
    rq[t] = pQ[(size_t)t * C + c];
    __syncthreads();
    for (int st = 64; st; st >>= 1) {
        if (t < st) { rs[t] += rs[t + st]; rq[t] += rq[t + st]; }
        __syncthreads();
    }
    if (t == 0) {
        float m = rs[0] / totalRows;
        mean[c] = m;
        var[c]  = rq[0] / totalRows - m * m;
    }
}

// ---------------- paired BN + ReLU + maxpool (channel-last) ----------------
static __device__ __forceinline__ void bnp_body(
    const float* __restrict__ X, const float* __restrict__ mean,
    const float* __restrict__ var, const float* __restrict__ g,
    const float* __restrict__ bta, float* __restrict__ Of,
    unsigned short* __restrict__ Ob, int C, int Lin, int Lout, int Kp, int outBf, int idx) {
    if (idx >= Bn * Lout * C) return;
    int c = idx % C, j = (idx / C) % Lout, b = idx / (C * Lout);
    float sc = g[c] * rsqrtf(var[c] + 1e-5f);
    float sh = bta[c] - mean[c] * sc;
    const float* xb = X + ((size_t)b * Lin + j * 2) * C + c;
    float m = 0.f;
    for (int k = 0; k < Kp; ++k) m = fmaxf(m, xb[(size_t)k * C] * sc + sh);
    if (outBf) Ob[idx] = f2bf(m);
    else       Of[idx] = m;
}

__global__ void bnp_pair(
    const float* __restrict__ X1, const float* __restrict__ mean1,
    const float* __restrict__ var1, const float* __restrict__ g1,
    const float* __restrict__ b1, float* __restrict__ Of1,
    unsigned short* __restrict__ Ob1, int C1,
    const float* __restrict__ X2, const float* __restrict__ mean2,
    const float* __restrict__ var2, const float* __restrict__ g2,
    const float* __restrict__ b2, float* __restrict__ Of2,
    unsigned short* __restrict__ Ob2, int C2,
    int Lin, int Lout, int Kp, int outBf) {
    int id = blockIdx.x;
    const int nb1 = (Bn * Lout * C1 + 255) / 256;
    if (id < nb1)
        bnp_body(X1, mean1, var1, g1, b1, Of1, Ob1, C1, Lin, Lout, Kp, outBf,
                 id * 256 + threadIdx.x);
    else
        bnp_body(X2, mean2, var2, g2, b2, Of2, Ob2, C2, Lin, Lout, Kp, outBf,
                 (id - nb1) * 256 + threadIdx.x);
}

// ---------------- final gating ----------------
__global__ void final_dot(const float* __restrict__ Y2, const float* __restrict__ Z2,
                          const float* __restrict__ wy, const float* __restrict__ by,
                          const float* __restrict__ wz, const float* __restrict__ bz,
                          float* __restrict__ prod) {
    const int b = blockIdx.y, j = blockIdx.x, t = threadIdx.x;
    float p0 = 0, p1 = 0, q0 = 0, q1 = 0;
    const float* yrow = Y2 + (size_t)(b * 255 + j) * FOUT;
    const float* zrow = Z2 + (size_t)(b * 255 + j) * CCAT;
    for (int c = t; c < FOUT; c += 128) {
        float v = yrow[c];
        p0 += v * wy[c]; p1 += v * wy[FOUT + c];
    }
    for (int c = t; c < CCAT; c += 128) {
        float v = zrow[c];
        q0 += v * wz[c]; q1 += v * wz[CCAT + c];
    }
    __shared__ float r0[128], r1[128], r2[128], r3[128];
    r0[t] = p0; r1[t] = p1; r2[t] = q0; r3[t] = q1;
    __syncthreads();
    for (int s = 64; s; s >>= 1) {
        if (t < s) { r0[t] += r0[t + s]; r1[t] += r1[t + s]; r2[t] += r2[t + s]; r3[t] += r3[t + s]; }
        __syncthreads();
    }
    if (t == 0) {
        float y0 = r0[0] + by[0], y1 = r1[0] + by[1];
        float z0 = r2[0] + bz[0], z1 = r3[0] + bz[1];
        prod[((size_t)b * 255 + j) * 2 + 0] = y0 * z0;
        prod[((size_t)b * 255 + j) * 2 + 1] = y1 * z1;
    }
}

__global__ void final_out(const float* __restrict__ prod, float* __restrict__ out) {
    const int b = blockIdx.x, t = threadIdx.x;
    const int w = t >> 6, lane = t & 63;
    float s = 0.f;
    for (int j = lane; j < 255; j += 64) s += prod[((size_t)b * 255 + j) * 2 + w];
#pragma unroll
    for (int off = 32; off; off >>= 1) s += __shfl_down(s, off);
    if (lane == 0) out[b * 2 + w] = 1.f / (1.f + expf(-s / 255.f));
}

// ---------------- launch ----------------
extern "C" void kernel_launch(void* const* d_in, const int* in_sizes, int n_in,
                              void* d_out, int out_size, void* d_ws, size_t ws_size,
                              hipStream_t stream) {
    (void)in_sizes; (void)n_in; (void)out_size; (void)ws_size;
    const float* features = (const float*)d_in[0];
    const int*   src      = (const int*)d_in[1];
    const int*   dst      = (const int*)d_in[2];
    const int*   etype    = (const int*)d_in[3];
    const float* W_lin    = (const float*)d_in[4];
    const float* b_lin    = (const float*)d_in[5];
    const float* W_ih     = (const float*)d_in[6];
    const float* W_hh     = (const float*)d_in[7];
    const float* b_ih     = (const float*)d_in[8];
    const float* b_hh     = (const float*)d_in[9];
    const float* conv1_w  = (const float*)d_in[10];
    const float* conv1_b  = (const float*)d_in[11];
    const float* conv2_w  = (const float*)d_in[12];
    const float* conv2_b  = (const float*)d_in[13];
    const float* convc1_w = (const float*)d_in[14];
    const float* convc1_b = (const float*)d_in[15];
    const float* convc2_w = (const float*)d_in[16];
    const float* convc2_b = (const float*)d_in[17];
    const float* bn_g     = (const float*)d_in[18];
    const float* bn_b     = (const float*)d_in[19];
    const float* bnc_g    = (const float*)d_in[20];
    const float* bnc_b    = (const float*)d_in[21];
    const float* mlpy_w   = (const float*)d_in[22];
    const float* mlpy_b   = (const float*)d_in[23];
    const float* mlpz_w   = (const float*)d_in[24];
    const float* mlpz_b   = (const float*)d_in[25];

    float* ws = (float*)d_ws;
    // ---- layout (float offsets) ----
    float*          h      = ws;                                 // [0, 4.19M)
    unsigned short* Acat0  = (unsigned short*)(ws + 4194304);    // [16384][512] bf16
    float*          bufA   = ws + 8388608;                       // 12.58M
    float*          bufB   = ws + 20971520;                      // 12.58M
    unsigned short* Wlin_b = (unsigned short*)(ws + 33554432);   // [512][256]
    unsigned short* Whh_b  = (unsigned short*)(ws + 33554432) + 131072;  // [768][256]
    unsigned short* Wcat_b = (unsigned short*)(ws + 33554432) + 327680;  // [768][512]
    float*          bias_s = ws + 33950000;                      // 768 f (clean region)
    int*            ib     = (int*)(ws + 34000000);
    int* deg    = ib;
    int* cursor = ib + 16384;
    int* rowptr = ib + 32768;
    int* widx   = ib + 49160;
    float* sreg = ws + 34500000;
    float* meanY = sreg;                 // 256
    float* varY  = sreg + 256;           // 256
    float* meanZ = sreg + 512;           // 384
    float* varZ  = sreg + 896;           // 384
    float* pSy   = sreg + 1280;          // 128*256
    float* pQy   = sreg + 34048;         // 128*256
    float* pSz   = sreg + 66816;         // 128*384
    float* pQz   = sreg + 115968;        // 128*384
    float* prod  = sreg + 165120;        // [16][255][2]

    unsigned short* Whb   = (unsigned short*)bufA;               // [16384][512] bf16
    unsigned short* Acat1 = (unsigned short*)(bufA + 4194304);   // [16384][512] bf16 (ping-pong)
    const unsigned short* Whg = Whh_b + 512 * 256;               // rows 512..767 of Whh

    // ---- weight conversion + CSR build ----
    cvt_bf<<<512,  256, 0, stream>>>(W_lin, Wlin_b, 131072);
    cvt_bf<<<768,  256, 0, stream>>>(W_hh,  Whh_b,  196608);
    cvt_wcat<<<1536, 256, 0, stream>>>(W_ih, W_hh, Wcat_b);
    add_bias<<<3, 256, 0, stream>>>(b_ih, b_hh, bias_s, 768);
    pad_h<<<Nn * FOUT / 256, 256, 0, stream>>>(features, h, Acat0);

    hipMemsetAsync(deg, 0, 16384 * sizeof(int), stream);
    edge_count<<<NE / 256, 256, 0, stream>>>(dst, deg);
    scan_deg<<<1, 1024, 0, stream>>>(deg, rowptr, cursor);
    edge_fill<<<NE / 256, 256, 0, stream>>>(src, dst, etype, cursor, widx);

    // ---- GGNN steps (Acat ping-pong; STEPS even -> final h-half in Acat0) ----
    unsigned short* Acur = Acat0;
    unsigned short* Anxt = Acat1;
    for (int s6 = 0; s6 < STEPS; ++s6) {
        gemm128_swz<<<dim3(4, 128), 256, 0, stream>>>(
            Acur, Wlin_b, b_lin, Whb, 512, 512, 256);
        gather_agg<<<Nn, 64, 0, stream>>>(Whb, rowptr, widx, Acur);
        gemm_gru<<<dim3(4, 256), 256, 0, stream>>>(
            Acur, Wcat_b, Whg, bias_s, b_hh + 512, h, Anxt);
        unsigned short* tmp = Acur; Acur = Anxt; Anxt = tmp;
    }

    // ---- conv-phase layout (channel-last); Acat1 dead after last step ----
    unsigned short* cb    = (unsigned short*)ws;                 // [16384][384] bf16 (over dead h)
    float*          Yc1   = bufA;                                // [16352][256] f32
    unsigned short* P1y   = (unsigned short*)(bufA + 4186112);   // [8160][256] bf16
    float*          Yc2   = bufA + 5230592;                      // [8160][256] f32
    float*          Y2    = bufA + 7319552;                      // [4080][256] f32
    float*          Z2    = bufA + 8364032;                      // [4080][384] f32
    float*          Zc1   = bufB;                                // [16352][384] f32
    unsigned short* P1z   = (unsigned short*)(bufB + 6279168);   // [8160][384] bf16
    float*          Zc2   = bufB + 7845888;                      // [8160][384] f32
    unsigned short* Wcv   = (unsigned short*)(bufB + 11000000);
    unsigned short* c1b   = Wcv;                                 // [256][768]
    unsigned short* c2b   = Wcv + 196608;                        // [256][256]
    unsigned short* cc1b  = Wcv + 262144;                        // [384][1152]
    unsigned short* cc2b  = Wcv + 704512;                        // [384][384]

    cvt_wconv<<<768,  256, 0, stream>>>(conv1_w,  c1b,  FOUT, 3, FOUT * FOUT * 3);
    cvt_wconv<<<256,  256, 0, stream>>>(conv2_w,  c2b,  FOUT, 1, FOUT * FOUT);
    cvt_wconv<<<1728, 256, 0, stream>>>(convc1_w, cc1b, CCAT, 3, CCAT * CCAT * 3);
    cvt_wconv<<<576,  256, 0, stream>>>(convc2_w, cc2b, CCAT, 1, CCAT * CCAT);
    build_cb<<<Nn * CCAT / 256, 256, 0, stream>>>(Acat0, features, cb);

    const int rows1 = Bn * 1022;
    const int rows2 = Bn * 510;
    const int rpc1  = (rows1 + NCHUNK - 1) / NCHUNK;
    const int rpc2  = (rows2 + NCHUNK - 1) / NCHUNK;

    // ---- stage 1: conv1 Y & Z fused, BN stats fused, bnp fused ----
    gemm128_pair2<<<2 * 8 * Bn + 3 * 8 * Bn, 256, 0, stream>>>(
        Acat0, c1b, conv1_b, Yc1, FOUT, 512, 1024, 1022, FOUT, 768, 2, 8,
        cb, cc1b, convc1_b, Zc1, CCAT, 384, 1024, 1022, CCAT, 1152, 3, 8);
    bn_part_pair<<<(2 + 3) * NCHUNK, 256, 0, stream>>>(
        Yc1, pSy, pQy, FOUT, Zc1, pSz, pQz, CCAT, rows1, rpc1);
    bn_reduce_pair<<<FOUT + CCAT, 128, 0, stream>>>(
        pSy, pQy, meanY, varY, FOUT, pSz, pQz, meanZ, varZ, CCAT, rows1);
    {
        const int nb1 = (Bn * 510 * FOUT + 255) / 256;
        const int nb2 = (Bn * 510 * CCAT + 255) / 256;
        bnp_pair<<<nb1 + nb2, 256, 0, stream>>>(
            Yc1, meanY, varY, bn_g, bn_b, nullptr, P1y, FOUT,
            Zc1, meanZ, varZ, bnc_g, bnc_b, nullptr, P1z, CCAT, 1022, 510, 3, 1);
    }

    // ---- stage 2: conv2 Y & Z fused, BN stats fused, bnp fused ----
    gemm128_pair2<<<2 * 4 * Bn + 3 * 4 * Bn, 256, 0, stream>>>(
        P1y, c2b, conv2_b, Yc2, FOUT, 256, 510, 510, FOUT, 256, 2, 4,
        P1z, cc2b, convc2_b, Zc2, CCAT, 384, 510, 510, CCAT, 384, 3, 4);
    bn_part_pair<<<(2 + 3) * NCHUNK, 256, 0, stream>>>(
        Yc2, pSy, pQy, FOUT, Zc2, pSz, pQz, CCAT, rows2, rpc2);
    bn_reduce_pair<<<FOUT + CCAT, 128, 0, stream>>>(
        pSy, pQy, meanY, varY, FOUT, pSz, pQz, meanZ, varZ, CCAT, rows2);
    {
        const int nb1 = (Bn * 255 * FOUT + 255) / 256;
        const int nb2 = (Bn * 255 * CCAT + 255) / 256;
        bnp_pair<<<nb1 + nb2, 256, 0, stream>>>(
            Yc2, meanY, varY, bn_g, bn_b, Y2, nullptr, FOUT,
            Zc2, meanZ, varZ, bnc_g, bnc_b, Z2, nullptr, CCAT, 510, 255, 2, 0);
    }

    // ---- gating + mean + sigmoid ----
    final_dot<<<dim3(255, Bn), 128, 0, stream>>>(Y2, Z2, mlpy_w, mlpy_b, mlpz_w, mlpz_b, prod);
    final_out<<<Bn, 128, 0, stream>>>(prod, (float*)d_out);
}